// Round 4
// baseline (700.124 us; speedup 1.0000x reference)
//
#include <hip/hip_runtime.h>
#include <hip/hip_bf16.h>

#define NXCD 8

// sigmoid(x) = 1 / (1 + e^-x); __expf -> v_mul + v_exp_f32, rcpf -> v_rcp_f32.
__device__ __forceinline__ float sigmoidf_fast(float v) {
    return __builtin_amdgcn_rcpf(1.0f + __expf(-v));
}

// Raw fp32 atomic add with NO sc flags -> executes in the issuing XCD's L2
// (no fabric write-through). ONLY correct if every writer of this address is
// on the same XCD (we guarantee that via per-XCD partial buffers + XCC_ID).
__device__ __forceinline__ void l2_local_atomic_add(float* p, float v) {
    asm volatile("global_atomic_add_f32 %0, %1, off" :: "v"(p), "v"(v) : "memory");
}

template <bool LOCAL>
__global__ __launch_bounds__(256) void mesh_pass1_kernel(
    const float* __restrict__ points,
    const int*   __restrict__ adj,
    const float* __restrict__ W1, const float* __restrict__ b1,
    const float* __restrict__ W2, const float* __restrict__ b2,
    const float* __restrict__ W3, const float* __restrict__ b3,
    const float* __restrict__ W4, const float* __restrict__ b4,
    float* __restrict__ dst,     // LOCAL: partial[NXCD][n_points]; else: out[n_points]
    int n_points, int n_elems)
{
    const int e = blockIdx.x * 256 + threadIdx.x;
    if (e >= n_elems) return;

    // ---- gather: 3 vertex indices, 3 float2 coords ----
    const int i0 = adj[3 * e + 0];
    const int i1 = adj[3 * e + 1];
    const int i2 = adj[3 * e + 2];
    const float2* pts2 = (const float2*)points;
    const float2 p0 = pts2[i0];
    const float2 p1 = pts2[i1];
    const float2 p2 = pts2[i2];

    const float x[6] = { p0.x, p0.y, p1.x, p1.y, p2.x, p2.y };

    // Weight loads are wave-uniform -> scalar s_load into SGPRs (free).

    // ---- layer 1: 6 -> 8 ----
    float h[8], g[8];
    #pragma unroll
    for (int j = 0; j < 8; ++j) h[j] = b1[j];
    #pragma unroll
    for (int i = 0; i < 6; ++i) {
        const float xi = x[i];
        #pragma unroll
        for (int j = 0; j < 8; ++j) h[j] = fmaf(xi, W1[i * 8 + j], h[j]);
    }
    #pragma unroll
    for (int j = 0; j < 8; ++j) h[j] = sigmoidf_fast(h[j]);

    // ---- layer 2: 8 -> 8 ----
    #pragma unroll
    for (int j = 0; j < 8; ++j) g[j] = b2[j];
    #pragma unroll
    for (int i = 0; i < 8; ++i) {
        const float hi = h[i];
        #pragma unroll
        for (int j = 0; j < 8; ++j) g[j] = fmaf(hi, W2[i * 8 + j], g[j]);
    }
    #pragma unroll
    for (int j = 0; j < 8; ++j) g[j] = sigmoidf_fast(g[j]);

    // ---- layer 3: 8 -> 8 ----
    #pragma unroll
    for (int j = 0; j < 8; ++j) h[j] = b3[j];
    #pragma unroll
    for (int i = 0; i < 8; ++i) {
        const float gi = g[i];
        #pragma unroll
        for (int j = 0; j < 8; ++j) h[j] = fmaf(gi, W3[i * 8 + j], h[j]);
    }
    #pragma unroll
    for (int j = 0; j < 8; ++j) h[j] = sigmoidf_fast(h[j]);

    // ---- layer 4: 8 -> 3 ----
    float o0 = b4[0], o1 = b4[1], o2 = b4[2];
    #pragma unroll
    for (int i = 0; i < 8; ++i) {
        const float hi = h[i];
        o0 = fmaf(hi, W4[i * 3 + 0], o0);
        o1 = fmaf(hi, W4[i * 3 + 1], o1);
        o2 = fmaf(hi, W4[i * 3 + 2], o2);
    }
    o0 = sigmoidf_fast(o0);
    o1 = sigmoidf_fast(o1);
    o2 = sigmoidf_fast(o2);

    if (LOCAL) {
        // Physical XCD id of this workgroup (HW-verified readable on gfx950).
        unsigned xcc;
        asm volatile("s_getreg_b32 %0, hwreg(HW_REG_XCC_ID)" : "=s"(xcc));
        float* part = dst + (size_t)(xcc & (NXCD - 1)) * n_points;
        l2_local_atomic_add(&part[i0], o0);
        l2_local_atomic_add(&part[i1], o1);
        l2_local_atomic_add(&part[i2], o2);
    } else {
        // Fallback: device-scope HW atomics straight into out.
        unsafeAtomicAdd(&dst[i0], o0);
        unsafeAtomicAdd(&dst[i1], o1);
        unsafeAtomicAdd(&dst[i2], o2);
    }
}

// out[v] = sum over the NXCD partial copies. Plain coalesced loads/stores.
__global__ __launch_bounds__(256) void mesh_pass2_kernel(
    const float* __restrict__ part, float* __restrict__ out, int n_points)
{
    const int i = (blockIdx.x * 256 + threadIdx.x) * 4;  // 4 vertices per thread
    if (i >= n_points) return;
    float4 s = make_float4(0.f, 0.f, 0.f, 0.f);
    #pragma unroll
    for (int c = 0; c < NXCD; ++c) {
        const float4 v = *(const float4*)(part + (size_t)c * n_points + i);
        s.x += v.x; s.y += v.y; s.z += v.z; s.w += v.w;
    }
    *(float4*)(out + i) = s;
}

extern "C" void kernel_launch(void* const* d_in, const int* in_sizes, int n_in,
                              void* d_out, int out_size, void* d_ws, size_t ws_size,
                              hipStream_t stream) {
    const float* points = (const float*)d_in[0];
    const int*   adj    = (const int*)d_in[1];
    const float* W1 = (const float*)d_in[2];
    const float* b1 = (const float*)d_in[3];
    const float* W2 = (const float*)d_in[4];
    const float* b2 = (const float*)d_in[5];
    const float* W3 = (const float*)d_in[6];
    const float* b3 = (const float*)d_in[7];
    const float* W4 = (const float*)d_in[8];
    const float* b4 = (const float*)d_in[9];
    float* out = (float*)d_out;

    const int n_elems  = in_sizes[1] / 3;  // adjacency is [E,3]
    const int n_points = out_size;

    const int block = 256;
    const int grid1 = (n_elems + block - 1) / block;

    const size_t need = (size_t)NXCD * n_points * sizeof(float);
    if (ws_size >= need && (n_points % 4) == 0) {
        float* part = (float*)d_ws;
        // zero the per-XCD partials (d_ws is re-poisoned before every launch)
        hipMemsetAsync(part, 0, need, stream);
        mesh_pass1_kernel<true><<<grid1, block, 0, stream>>>(
            points, adj, W1, b1, W2, b2, W3, b3, W4, b4, part, n_points, n_elems);
        const int grid2 = (n_points / 4 + block - 1) / block;
        mesh_pass2_kernel<<<grid2, block, 0, stream>>>(part, out, n_points);
    } else {
        // Fallback: original single-pass device-scope atomics.
        hipMemsetAsync(out, 0, (size_t)n_points * sizeof(float), stream);
        mesh_pass1_kernel<false><<<grid1, block, 0, stream>>>(
            points, adj, W1, b1, W2, b2, W3, b3, W4, b4, out, n_points, n_elems);
    }
}